// Round 3
// baseline (5508.432 us; speedup 1.0000x reference)
//
#include <hip/hip_runtime.h>

// ============================================================================
// Persistent dataflow kernel for attention-LSTM encoder.
// B=512, T-1=99, N=128, H=256. f32 global I/O, bf16 LDS/MFMA internals.
//
// R8: R6/R7 was exchange-volume-bound: z1 k-partials were 14 MB/step of
// L2-miss traffic (hbm_bytes 1.43e9, 322 GB/s -> 44.8 us/step == measured).
// Fix: zero z1 exchange. Each A-block computes z1 for its OWN batch locally:
//   - own h,c (1 KB bf16) read from hbuf under the existing flagB wait
//     (c restored into hbuf, +256KB/step)
//   - W1 pre-converted to bf16 (101 KB) by a converter kernel launched
//     before enc_kernel; read-only -> L2-resident per XCD, ordinary loads
//   - lane-per-8k dot products: hc in 8 f32 regs/lane, one coalesced 16B
//     W1 row load per lane per s, 6-shuffle reduce; ~25 s per wave
// B phase loses the 14 z1p MFMAs + stores. Topology stays 2 hops:
//   flagB -> A(local z1 + attn) -> flagA -> B(gates+LSTM) -> flagB
// Per-step cross-block writes: hc 512KB + w 128KB (vs R6's 8MB).
//
// 512 blocks x 256 threads, 2 blocks/CU (LDS ~58KB => all 512 co-resident).
// Each 32-block group is a closed dependency system => deadlock-free
// (same flag protocol as R6/R7, which ran to completion and verified).
// ============================================================================

typedef unsigned int  uint32;
typedef unsigned long long ull;
typedef unsigned short u16;
typedef float  f4  __attribute__((ext_vector_type(4)));
typedef short  s8v __attribute__((ext_vector_type(8)));   // 8 bf16

#define TS 99
#define BB 512
#define NN 128
#define HH 256

__device__ __forceinline__ float bf2f(u16 u){
  union { uint32 i; float f; } v; v.i = ((uint32)u) << 16; return v.f;
}
__device__ __forceinline__ u16 f2bf(float f){
  union { float f; uint32 i; } v; v.f = f;
  uint32 r = v.i + 0x7FFFu + ((v.i >> 16) & 1u);   // RNE (finite values only)
  return (u16)(r >> 16);
}
__device__ __forceinline__ float frcp(float x){ return __builtin_amdgcn_rcpf(x); }
__device__ __forceinline__ float ftanh(float x){
  float t = __expf(2.f * x);
  return 1.f - 2.f * frcp(t + 1.f);
}
__device__ __forceinline__ float fsig(float x){
  return frcp(1.f + __expf(-x));
}

// L3-coherence-point accesses (sc1; bypass per-XCD L2, no cache maintenance)
__device__ __forceinline__ uint32 ld32(const uint32* p){
  return __hip_atomic_load(p, __ATOMIC_RELAXED, __HIP_MEMORY_SCOPE_AGENT);
}
__device__ __forceinline__ ull ld64(const ull* p){
  return __hip_atomic_load(p, __ATOMIC_RELAXED, __HIP_MEMORY_SCOPE_AGENT);
}
__device__ __forceinline__ void st32(uint32* p, uint32 v){
  __hip_atomic_store(p, v, __ATOMIC_RELAXED, __HIP_MEMORY_SCOPE_AGENT);
}
__device__ __forceinline__ void st64(ull* p, ull v){
  __hip_atomic_store(p, v, __ATOMIC_RELAXED, __HIP_MEMORY_SCOPE_AGENT);
}

struct KParams {
  const float *in, *W1, *b1, *W2, *b2, *W3, *Wih, *Whh, *bih, *bhh;
  float *out;        // [weighted B*99*128 | encoded B*99*256] f32
  uint32 *flagA;     // [512]  A(t) done -> w published
  uint32 *flagB;     // [16]   counts B-phase completions per group
  u16 *hbuf;         // [2][512][512] bf16: per batch h[256] | c[256]
  u16 *wbf;          // [512][128] bf16 (single-buffer, race-safe via flags)
  const u16 *w1bf;   // [99][512] bf16 W1 (written by converter kernel)
};

// ---- converter: W1 f32 -> bf16 (runs once, before enc_kernel) ----
__global__ void w1conv_kernel(const float* W1, u16* w1bf)
{
  int idx = blockIdx.x * 256 + threadIdx.x;
  if (idx < TS * 512) w1bf[idx] = f2bf(W1[idx]);
}

__global__ __launch_bounds__(256, 2) void enc_kernel(KParams p)
{
  __shared__ __align__(16) u16   z2s[128 * 100];   // z2[n][s] bf16 (+b2)
  __shared__ __align__(16) u16   ubuf[12800];      // in_t[128][100] then Wsl[32][392]
  __shared__ __align__(16) u16   hcn[32 * 16];     // bf16 per-batch [h0..7|c0..7]
  __shared__ __align__(16) float uni[1056];        // e partials | gates[32][33]
  __shared__ __align__(16) float z1s[100];
  __shared__ __align__(16) float w3s[100];
  __shared__ __align__(16) float b1s[100];
  __shared__ __align__(16) float biasv[32];

  const int tid = threadIdx.x;
  const int blk = blockIdx.x;
  const int bA  = blk;        // A-role batch
  const int bg  = blk >> 5;   // group of 32 batches / 32 blocks
  const int js  = blk & 31;   // B-role unit slice (units js*8 .. js*8+7)

  float* outw = p.out;
  float* oute = p.out + (size_t)BB * TS * NN;

  // wave-role constants (MFMA lane mapping, R4/R5-verified)
  const int wv   = tid >> 6, lane = tid & 63;
  const int mi   = wv & 1,   ni   = wv >> 1;
  const int bb   = bg * 32 + mi * 16 + (lane & 15);
  const int q8   = (lane >> 4) * 8;
  const int m15  = lane & 15;
  const int nr   = ni * 16 + m15;

  // ---------------- prologue ----------------
  {
    const float* src = p.in + (size_t)bA * TS * NN;
    for (int idx = tid; idx < TS * NN; idx += 256) {
      int t = idx >> 7, n = idx & 127;
      ubuf[n * 100 + t] = f2bf(src[idx]);
    }
  }
  __syncthreads();
  {  // z2s[n][s] = b2[s] + sum_t in_t[n][t] * W2[s][t]
    int n = tid >> 1, sc = tid & 1;
    int s0 = sc * 50, s1 = sc ? 99 : 50;
    for (int s = s0; s < s1; ++s) {
      float acc = p.b2[s];
      const float* w2r = p.W2 + s * TS;
      const u16* itr = &ubuf[n * 100];
      for (int t = 0; t + 1 < TS; t += 2) {
        acc = fmaf(bf2f(itr[t]),     w2r[t],     acc);
        acc = fmaf(bf2f(itr[t + 1]), w2r[t + 1], acc);
      }
      acc = fmaf(bf2f(itr[98]), w2r[98], acc);
      z2s[n * 100 + s] = f2bf(acc);
    }
  }
  __syncthreads();
  {  // Wsl[32 rows][392] into ubuf; small vectors
    int r = tid >> 3;
    int g = r >> 3, ul = r & 7;
    int grow = g * 256 + js * 8 + ul;
    const float* wihr = p.Wih + (size_t)grow * 128;
    const float* whhr = p.Whh + (size_t)grow * 256;
    for (int k = tid & 7; k < 384; k += 8)
      ubuf[r * 392 + k] = f2bf((k < 128) ? wihr[k] : whhr[k - 128]);
    if (tid < 32) {
      int g2 = tid >> 3, ul2 = tid & 7;
      int gr = g2 * 256 + js * 8 + ul2;
      biasv[tid] = p.bih[gr] + p.bhh[gr];
    }
    for (int s = tid; s < 99; s += 256) {
      w3s[s] = p.W3[s];
      b1s[s] = p.b1[s];
    }
  }
  __syncthreads();

  float creg = 0.f;   // LSTM cell state for (lb=tid>>3, ul=tid&7), fp32 forever

  for (int t = 0; t < TS; ++t) {
    const int par = t & 1;

    // ---- single wait: h,c(t-1) of own group ready ----
    if (t > 0) {
      if (tid == 0) {
        uint32 tgt = 32u * (uint32)t;
        while (ld32(&p.flagB[bg]) < tgt) __builtin_amdgcn_s_sleep(1);
      }
      __syncthreads();
    }

    // ---- prefetch gates h-operand fragments (consumed in B phase) ----
    ull hq0[8], hq1[8];
    {
      const ull* hrow = (const ull*)(p.hbuf + ((size_t)par * BB + bb) * 512);
      #pragma unroll
      for (int ks = 0; ks < 8; ++ks) {
        int ei = ks * 32 + q8;
        hq0[ks] = ld64(hrow + (ei >> 2));
        hq1[ks] = ld64(hrow + (ei >> 2) + 1);
      }
    }

    // ================= A phase: attention for batch bA =================
    // z1[s] = b1[s] + sum_k hc[k] * W1[s][k]  -- fully local, no exchange.
    // lane owns k = lane*8..+8 (hc in regs); wave wv owns s = wv*25..(+25|24).
    if (t > 0) {
      float hcreg[8];
      {
        const ull* hcrow = (const ull*)(p.hbuf + ((size_t)par * BB + bA) * 512);
        ull a0 = ld64(hcrow + lane * 2);
        ull a1 = ld64(hcrow + lane * 2 + 1);
        union { ull q; u16 us[4]; } u0, u1;
        u0.q = a0; u1.q = a1;
        #pragma unroll
        for (int j = 0; j < 4; ++j) {
          hcreg[j]     = bf2f(u0.us[j]);
          hcreg[4 + j] = bf2f(u1.us[j]);
        }
      }
      int s0  = wv * 25;
      int cnt = (wv == 3) ? 24 : 25;
      for (int i = 0; i < cnt; ++i) {
        int s = s0 + i;
        const s8v* wrow = (const s8v*)(p.w1bf + (size_t)s * 512 + lane * 8);
        s8v wb = *wrow;   // ordinary load: read-only, L2-resident
        float acc = 0.f;
        #pragma unroll
        for (int j = 0; j < 8; ++j)
          acc = fmaf(hcreg[j], bf2f((u16)wb[j]), acc);
        #pragma unroll
        for (int off = 32; off; off >>= 1) acc += __shfl_xor(acc, off);
        if (lane == 0) z1s[s] = b1s[s] + acc;
      }
    } else {
      if (tid < TS) z1s[tid] = b1s[tid];   // h=c=0 at t=0
    }
    __syncthreads();

    {  // e[n] = sum_s w3[s] * tanh(z1[s] + z2[n][s])
      int n = tid >> 1, hfb = tid & 1;
      int s0 = hfb * 50, s1 = hfb ? 99 : 50;
      const u16* z2r = &z2s[n * 100];
      float acc = 0.f;
      for (int s = s0; s < s1; ++s) {
        float x = ftanh(z1s[s] + bf2f(z2r[s]));
        acc = fmaf(w3s[s], x, acc);
      }
      uni[tid] = acc;
    }
    __syncthreads();
    // softmax + w, all in wave 0
    float* efin = uni + 256;
    if (tid < 64) {
      float v0 = uni[2 * tid]        + uni[2 * tid + 1];
      float v1 = uni[2 * (tid + 64)] + uni[2 * (tid + 64) + 1];
      efin[tid] = v0; efin[tid + 64] = v1;
      float m = fmaxf(v0, v1);
      for (int off = 32; off; off >>= 1) m = fmaxf(m, __shfl_xor(m, off));
      float sm = __expf(v0 - m) + __expf(v1 - m);
      for (int off = 32; off; off >>= 1) sm += __shfl_xor(sm, off);
      float r = frcp(sm);
      float e0 = efin[2 * tid], e1 = efin[2 * tid + 1];
      const float* xr = p.in + ((size_t)bA * TS + t) * NN + 2 * tid;
      float w0 = __expf(e0 - m) * r * xr[0];
      float w1 = __expf(e1 - m) * r * xr[1];
      float* orow = outw + ((size_t)bA * TS + t) * NN + 2 * tid;
      orow[0] = w0; orow[1] = w1;                      // f32 output
      st32((uint32*)p.wbf + (size_t)bA * 64 + tid,     // bf16 pair, sc1
           (uint32)f2bf(w0) | ((uint32)f2bf(w1) << 16));
    }
    __builtin_amdgcn_s_waitcnt(0);   // drain wave-0 w-stores to L3
    if (tid == 0) st32(&p.flagA[bA], (uint32)(t + 1));

    // ================= B phase: gates+LSTM for (bg, js) =================
    const u16* wslr = &ubuf[nr * 392];
    f4 acc = {0.f, 0.f, 0.f, 0.f};
    #pragma unroll
    for (int ks = 0; ks < 8; ++ks) {   // h-part (fragments already in regs)
      union { ull q[2]; s8v v; } a; a.q[0] = hq0[ks]; a.q[1] = hq1[ks];
      const s8v* bp = (const s8v*)(wslr + 128 + ks * 32 + q8);
      acc = __builtin_amdgcn_mfma_f32_16x16x32_bf16(a.v, *bp, acc, 0, 0, 0);
    }
    if (tid < 32) {   // wait: all A(t) of the group published w
      uint32 tgt = (uint32)(t + 1);
      while (ld32(&p.flagA[bg * 32 + tid]) < tgt) __builtin_amdgcn_s_sleep(1);
    }
    __syncthreads();
    {
      const ull* wrow = (const ull*)(p.wbf + (size_t)bb * NN);
      #pragma unroll
      for (int ks = 0; ks < 4; ++ks) {  // w-part
        int ei = ks * 32 + q8;
        union { ull q[2]; s8v v; } a;
        a.q[0] = ld64(wrow + (ei >> 2));
        a.q[1] = ld64(wrow + (ei >> 2) + 1);
        const s8v* bp = (const s8v*)(wslr + ei);
        acc = __builtin_amdgcn_mfma_f32_16x16x32_bf16(a.v, *bp, acc, 0, 0, 0);
      }
      int mrow = mi * 16 + (lane >> 4) * 4;
      #pragma unroll
      for (int i = 0; i < 4; ++i) uni[(mrow + i) * 33 + nr] = acc[i];
    }
    __syncthreads();
    {  // LSTM pointwise: thread = (lb, ul); hcn gets bf16 h|c directly
      int lb = tid >> 3, ul = tid & 7;
      float iv = uni[lb * 33 + ul]      + biasv[ul];
      float fv = uni[lb * 33 + 8 + ul]  + biasv[8 + ul];
      float gv = uni[lb * 33 + 16 + ul] + biasv[16 + ul];
      float ov = uni[lb * 33 + 24 + ul] + biasv[24 + ul];
      float cn = fsig(fv) * creg + fsig(iv) * ftanh(gv);
      float hn = fsig(ov) * ftanh(cn);
      creg = cn;
      int bb2 = bg * 32 + lb, u = js * 8 + ul;
      oute[((size_t)bb2 * TS + t) * HH + u] = hn;   // f32 output
      hcn[lb * 16 + ul]     = f2bf(hn);
      hcn[lb * 16 + 8 + ul] = f2bf(cn);
    }
    __syncthreads();

    // ---- publish h AND c (bf16, coalesced) for step t+1 ----
    if (tid < 128) {
      int q  = tid & 63;
      int lb = q >> 1, half = q & 1;
      int coff = (tid < 64) ? 0 : 8;                 // hcn: h at +0, c at +8
      ull pk = *(const ull*)&hcn[lb * 16 + coff + half * 4];
      int uoff = ((tid < 64) ? 0 : 256) + js * 8;
      ull* hp = (ull*)(p.hbuf
                + (((size_t)((t + 1) & 1)) * BB + bg * 32 + lb) * 512 + uoff);
      st64(hp + half, pk);
    }
    __builtin_amdgcn_s_waitcnt(0);   // drain this wave's h/c stores
    __syncthreads();                 // all waves drained
    if (tid == 0)
      __hip_atomic_fetch_add(&p.flagB[bg], 1u, __ATOMIC_RELAXED,
                             __HIP_MEMORY_SCOPE_AGENT);
  }
}

extern "C" void kernel_launch(void* const* d_in, const int* in_sizes, int n_in,
                              void* d_out, int out_size, void* d_ws, size_t ws_size,
                              hipStream_t stream)
{
  KParams p;
  p.in  = (const float*)d_in[0];
  p.W1  = (const float*)d_in[1];
  p.b1  = (const float*)d_in[2];
  p.W2  = (const float*)d_in[3];
  p.b2  = (const float*)d_in[4];
  p.W3  = (const float*)d_in[5];
  // d_in[6] = b3: softmax shift-invariant, unused
  p.Wih = (const float*)d_in[7];
  p.Whh = (const float*)d_in[8];
  p.bih = (const float*)d_in[9];
  p.bhh = (const float*)d_in[10];
  p.out = (float*)d_out;

  char* ws = (char*)d_ws;
  const size_t offFlagB  = 2048;
  const size_t offHbuf   = 4096;
  const size_t hbufBytes = 2ull * BB * 512 * 2;                // 1,048,576
  const size_t offWbf    = offHbuf + hbufBytes;                // 1,052,672
  const size_t wbfBytes  = (size_t)BB * NN * 2;                // 131,072
  const size_t offW1bf   = offWbf + wbfBytes;                  // 1,183,744
  const size_t w1bfBytes = (size_t)TS * 512 * 2;               // 101,376
  const size_t needBytes = offW1bf + w1bfBytes;                // ~1.29 MB
  if (ws_size < needBytes) return;  // fail loudly (poisoned output)

  p.flagA = (uint32*)ws;
  p.flagB = (uint32*)(ws + offFlagB);
  p.hbuf  = (u16*)(ws + offHbuf);
  p.wbf   = (u16*)(ws + offWbf);
  p.w1bf  = (const u16*)(ws + offW1bf);

  // zero flags + hbuf + wbf (w1bf is fully written by the converter kernel;
  // cross-kernel visibility guaranteed by same-stream kernel ordering)
  hipMemsetAsync(d_ws, 0, offW1bf, stream);
  w1conv_kernel<<<dim3((TS * 512 + 255) / 256), dim3(256), 0, stream>>>(
      p.W1, (u16*)(ws + offW1bf));

  enc_kernel<<<dim3(512), dim3(256), 0, stream>>>(p);
}

// Round 4
// 1412.535 us; speedup vs baseline: 3.8997x; 3.8997x over previous
//
#include <hip/hip_runtime.h>

// ============================================================================
// Fully block-local attention-LSTM encoder. B=512, T-1=99, N=128, H=256.
//
// R9: R5-R8 all bound by cross-block flag exchange latency (33-56 us/step,
// VALUBusy ~9%, everything idle). Key realization: the recurrence is
// PER-BATCH INDEPENDENT — no cross-batch coupling anywhere. So: 256 blocks
// x 512 threads, each block owns 2 batches end-to-end; h,c,z2 stay in
// LDS/registers; weights (Wih|Whh 786KB + W1 131KB, f16-pair packed,
// k-major coalesced layout) are STREAMED from L2 each step (read-only,
// shared by all 32 blocks of an XCD -> L2-resident). ZERO inter-block
// sync: no flags, no sc1, no store drains. ~6 __syncthreads per step.
// Floor: 0.92 MB/step/CU / ~135 GB/s L2 = ~6.8 us/step + overlapped compute.
//
// f16 (not bf16) for all packed internals: same bytes, 3 more mantissa bits;
// v_dot2_f32_f16 gives 2 MAC/lane/instr for the matvecs. Accumulation f32.
// c never leaves registers (f32); h,c rounded to f16 only as matvec inputs
// (previously bf16 -> accuracy improves or holds).
// ============================================================================

typedef unsigned int  uint32;
typedef unsigned short u16;
typedef _Float16 h2  __attribute__((ext_vector_type(2)));
typedef uint32   u4  __attribute__((ext_vector_type(4)));

#define TS 99
#define BB 512
#define NN 128
#define HH 256

__device__ __forceinline__ float frcp(float x){ return __builtin_amdgcn_rcpf(x); }
__device__ __forceinline__ float ftanh(float x){
  float t = __expf(2.f * x);
  return 1.f - 2.f * frcp(t + 1.f);
}
__device__ __forceinline__ float fsig(float x){
  return frcp(1.f + __expf(-x));
}
__device__ __forceinline__ uint32 pk2(float a, float b){
  union { h2 h; uint32 u; } v;
  v.h[0] = (_Float16)a; v.h[1] = (_Float16)b; return v.u;
}
__device__ __forceinline__ float h2ff(u16 u){
  union { u16 us; _Float16 h; } v; v.us = u; return (float)v.h;
}
__device__ __forceinline__ float dot2(uint32 a, uint32 b, float c){
  union { uint32 u; h2 h; } x, y; x.u = a; y.u = b;
#if __has_builtin(__builtin_amdgcn_fdot2)
  return __builtin_amdgcn_fdot2(x.h, y.h, c, false);
#else
  c = fmaf((float)x.h[0], (float)y.h[0], c);
  return fmaf((float)x.h[1], (float)y.h[1], c);
#endif
}

struct KParams {
  const float *in, *W1, *b1, *W2, *b2, *W3, *Wih, *Whh, *bih, *bhh;
  float *out;           // [weighted B*99*128 | encoded B*99*256] f32
  const uint32 *Wg4;    // [48][1024][4] f16-pairs: row j = [Wih(64p)|Whh(128p)]
  const uint32 *W1c4;   // [64][128][4]  f16-pairs: W1[s][k], kp-major, s padded
};

// ---- pack weights to f16 pairs, k-major coalesced layouts (runs once) ----
__global__ void pack_kernel(const float* W1, const float* Wih, const float* Whh,
                            uint32* Wg4, uint32* W1c4)
{
  int idx = blockIdx.x * 256 + threadIdx.x;
  if (idx < 48 * 1024 * 4) {
    // Wg4[kb][j][i]: pair p = kb*4+i of combined row j (Wih 64 pairs, Whh 128)
    int i = idx & 3, j = (idx >> 2) & 1023, kb = idx >> 12;
    int pp = kb * 4 + i;
    float a, b;
    if (pp < 64) { a = Wih[j * 128 + 2 * pp];       b = Wih[j * 128 + 2 * pp + 1]; }
    else { int q = pp - 64; a = Whh[j * 256 + 2 * q]; b = Whh[j * 256 + 2 * q + 1]; }
    Wg4[idx] = pk2(a, b);
  } else {
    int v = idx - 48 * 1024 * 4;
    if (v < 64 * 128 * 4) {
      // W1c4[kpb][s][i]: pair kp = kpb*4+i of W1 row s (512 k = 256 pairs)
      int i = v & 3, s = (v >> 2) & 127, kpb = v >> 9;
      int kp = kpb * 4 + i;
      uint32 r = 0;
      if (s < TS) r = pk2(W1[(size_t)s * 512 + 2 * kp],
                          W1[(size_t)s * 512 + 2 * kp + 1]);
      W1c4[v] = r;
    }
  }
}

__global__ __launch_bounds__(512, 1) void enc_kernel(KParams p)
{
  // stride 102 (odd dword count) -> LDS bank spread for per-row u16 reads
  __shared__ u16    int_s[2][128][102];  // f16 in[b][n][t] (prologue staging)
  __shared__ u16    z2s[2][128][102];    // f16 z2[b][n][s] (+b2)
  __shared__ uint32 hcp[2][256];         // f16 pairs: h (0..127) | c (128..255)
  __shared__ uint32 wp[2][64];           // f16 pairs: w[n] (attention output)
  __shared__ float  z1part[2][4][128];
  __shared__ float  z1s[2][128];
  __shared__ float  epart[2][2][128];
  __shared__ float  gl[2][1024];
  __shared__ float  biasl[1024];
  __shared__ float  w3s[128], b1s[128];

  const int tid = threadIdx.x;
  const int blk = blockIdx.x;
  const int b0  = blk * 2;               // this block's two batches

  float* outw = p.out;
  float* oute = p.out + (size_t)BB * TS * NN;

  // ---------------- prologue ----------------
  for (int b = 0; b < 2; ++b) {          // stage inputs f16, column layout
    const float* src = p.in + (size_t)(b0 + b) * TS * NN;
    for (int idx = tid; idx < TS * NN; idx += 512) {
      int t = idx >> 7, n = idx & 127;
      int_s[b][n][t] = (u16)(pk2(src[idx], 0.f) & 0xFFFFu);
    }
  }
  if (tid < 128) {
    w3s[tid] = (tid < TS) ? p.W3[tid] : 0.f;
    b1s[tid] = (tid < TS) ? p.b1[tid] : 0.f;
  }
  hcp[tid >> 8][tid & 255] = 0;          // h = c = 0 at t=0
  biasl[tid]       = p.bih[tid]       + p.bhh[tid];
  biasl[tid + 512] = p.bih[tid + 512] + p.bhh[tid + 512];
  __syncthreads();
  {  // z2[b][n][s] = b2[s] + sum_t in[b][t][n] * W2[s][t]
    int n = tid & 127, b = (tid >> 7) & 1, hf = tid >> 8;
    int s0 = hf * 50, s1 = hf ? TS : 50;
    const u16* ir = int_s[b][n];
    for (int s = s0; s < s1; ++s) {
      float acc = p.b2[s];
      const float* w2r = p.W2 + s * TS;
      for (int tt = 0; tt + 1 < TS; tt += 2) {
        uint32 pr = *(const uint32*)&ir[tt];
        union { uint32 u; h2 h; } v; v.u = pr;
        acc = fmaf((float)v.h[0], w2r[tt],     acc);
        acc = fmaf((float)v.h[1], w2r[tt + 1], acc);
      }
      acc = fmaf(h2ff(ir[98]), w2r[98], acc);
      z2s[b][n][s] = (u16)(pk2(acc, 0.f) & 0xFFFFu);
    }
  }
  __syncthreads();

  float creg = 0.f;                      // c for (lb, lu), f32 forever
  const int lu = tid & 255, lb = tid >> 8;

  for (int t = 0; t < TS; ++t) {
    // ===== Z1: z1[b][s] = b1[s] + [h,c] . W1[s][:]  (f16 dot2, streamed) ====
    {
      int s = tid & 127, q = tid >> 7;   // q = k-quarter (64 pairs each)
      float a0 = 0.f, a1 = 0.f;
      #pragma unroll 4
      for (int kk = 0; kk < 16; ++kk) {
        int kpb = q * 16 + kk;
        u4 w  = *(const u4*)(p.W1c4 + ((size_t)kpb * 128 + s) * 4);
        u4 x0 = *(const u4*)&hcp[0][kpb * 4];   // LDS broadcast
        u4 x1 = *(const u4*)&hcp[1][kpb * 4];
        #pragma unroll
        for (int i = 0; i < 4; ++i) {
          a0 = dot2(w[i], x0[i], a0);
          a1 = dot2(w[i], x1[i], a1);
        }
      }
      z1part[0][q][s] = a0;
      z1part[1][q][s] = a1;
    }
    __syncthreads();
    if (tid < 256) {
      int b = tid >> 7, s = tid & 127;
      z1s[b][s] = b1s[s] + ((z1part[b][0][s] + z1part[b][1][s])
                          + (z1part[b][2][s] + z1part[b][3][s]));
    }
    __syncthreads();

    // ===== E: e[b][n] = sum_s w3[s] * tanh(z1[b][s] + z2[b][n][s]) =========
    {
      int n = tid & 127, b = (tid >> 7) & 1, hf = tid >> 8;
      int s0 = hf * 50, s1 = hf ? TS : 50;
      const u16* zr = z2s[b][n];
      float acc = 0.f;
      for (int s = s0; s < s1; ++s)
        acc = fmaf(w3s[s], ftanh(z1s[b][s] + h2ff(zr[s])), acc);
      epart[b][hf][n] = acc;
    }
    __syncthreads();

    // ===== softmax + w = attn * x_t  (wave 0 -> batch 0, wave 1 -> batch 1)
    if (tid < 128) {
      int b = tid >> 6, lane = tid & 63;
      float v0 = epart[b][0][lane]      + epart[b][1][lane];
      float v1 = epart[b][0][lane + 64] + epart[b][1][lane + 64];
      float m = fmaxf(v0, v1);
      for (int off = 32; off; off >>= 1) m = fmaxf(m, __shfl_xor(m, off));
      float e0 = __expf(v0 - m), e1 = __expf(v1 - m);
      float sm = e0 + e1;
      for (int off = 32; off; off >>= 1) sm += __shfl_xor(sm, off);
      float r = frcp(sm);
      const float* xr = p.in + ((size_t)(b0 + b) * TS + t) * NN;
      float w0 = e0 * r * xr[lane];
      float w1 = e1 * r * xr[lane + 64];
      float* orow = outw + ((size_t)(b0 + b) * TS + t) * NN;
      orow[lane]      = w0;              // f32 output
      orow[lane + 64] = w1;
      float w0n = __shfl_xor(w0, 1), w1n = __shfl_xor(w1, 1);
      if ((lane & 1) == 0) {             // pack adjacent-n pairs as f16x2
        wp[b][lane >> 1]        = pk2(w0, w0n);
        wp[b][32 + (lane >> 1)] = pk2(w1, w1n);
      }
    }
    __syncthreads();

    // ===== gates: g[b][j] = w.Wih[j] + h.Whh[j] + bias[j]  (streamed) ======
    {
      float a00 = 0.f, a01 = 0.f, a10 = 0.f, a11 = 0.f;  // [batch][j-half]
      const uint32* wg = p.Wg4;
      #pragma unroll 4
      for (int kb = 0; kb < 16; ++kb) {  // w-part (pairs 0..63)
        u4 w0 = *(const u4*)(wg + ((size_t)kb * 1024 + tid) * 4);
        u4 w1 = *(const u4*)(wg + ((size_t)kb * 1024 + tid + 512) * 4);
        u4 x0 = *(const u4*)&wp[0][kb * 4];
        u4 x1 = *(const u4*)&wp[1][kb * 4];
        #pragma unroll
        for (int i = 0; i < 4; ++i) {
          a00 = dot2(w0[i], x0[i], a00); a01 = dot2(w1[i], x0[i], a01);
          a10 = dot2(w0[i], x1[i], a10); a11 = dot2(w1[i], x1[i], a11);
        }
      }
      #pragma unroll 4
      for (int kb = 16; kb < 48; ++kb) { // h-part (h pairs 0..127)
        u4 w0 = *(const u4*)(wg + ((size_t)kb * 1024 + tid) * 4);
        u4 w1 = *(const u4*)(wg + ((size_t)kb * 1024 + tid + 512) * 4);
        u4 x0 = *(const u4*)&hcp[0][(kb - 16) * 4];
        u4 x1 = *(const u4*)&hcp[1][(kb - 16) * 4];
        #pragma unroll
        for (int i = 0; i < 4; ++i) {
          a00 = dot2(w0[i], x0[i], a00); a01 = dot2(w1[i], x0[i], a01);
          a10 = dot2(w0[i], x1[i], a10); a11 = dot2(w1[i], x1[i], a11);
        }
      }
      gl[0][tid]       = a00 + biasl[tid];
      gl[0][tid + 512] = a01 + biasl[tid + 512];
      gl[1][tid]       = a10 + biasl[tid];
      gl[1][tid + 512] = a11 + biasl[tid + 512];
    }
    __syncthreads();

    // ===== LSTM pointwise; thread = (lb, lu) fixed across steps ============
    {
      float iv = gl[lb][lu],       fv = gl[lb][256 + lu];
      float gv = gl[lb][512 + lu], ov = gl[lb][768 + lu];
      float cn = fsig(fv) * creg + fsig(iv) * ftanh(gv);
      float hn = fsig(ov) * ftanh(cn);
      creg = cn;
      oute[((size_t)(b0 + lb) * TS + t) * HH + lu] = hn;   // f32 output
      float hx = __shfl_xor(hn, 1);      // lu parity == lane parity
      float cx = __shfl_xor(cn, 1);
      if ((lu & 1) == 0) {
        hcp[lb][lu >> 1]         = pk2(hn, hx);
        hcp[lb][128 + (lu >> 1)] = pk2(cn, cx);
      }
    }
    __syncthreads();
  }
}

extern "C" void kernel_launch(void* const* d_in, const int* in_sizes, int n_in,
                              void* d_out, int out_size, void* d_ws, size_t ws_size,
                              hipStream_t stream)
{
  KParams p;
  p.in  = (const float*)d_in[0];
  p.W1  = (const float*)d_in[1];
  p.b1  = (const float*)d_in[2];
  p.W2  = (const float*)d_in[3];
  p.b2  = (const float*)d_in[4];
  p.W3  = (const float*)d_in[5];
  // d_in[6] = b3: softmax shift-invariant, unused
  p.Wih = (const float*)d_in[7];
  p.Whh = (const float*)d_in[8];
  p.bih = (const float*)d_in[9];
  p.bhh = (const float*)d_in[10];
  p.out = (float*)d_out;

  char* ws = (char*)d_ws;
  const size_t wg4Bytes  = 48ull * 1024 * 4 * 4;   // 786,432
  const size_t w1c4Bytes = 64ull * 128 * 4 * 4;    // 131,072
  const size_t needBytes = wg4Bytes + w1c4Bytes;   // 917,504
  if (ws_size < needBytes) return;  // fail loudly (poisoned output)

  uint32* Wg4  = (uint32*)ws;
  uint32* W1c4 = (uint32*)(ws + wg4Bytes);
  p.Wg4  = Wg4;
  p.W1c4 = W1c4;

  // pack weights (writes fully cover both buffers; same-stream ordering
  // guarantees visibility to enc_kernel)
  pack_kernel<<<dim3(896), dim3(256), 0, stream>>>(p.W1, p.Wih, p.Whh,
                                                   Wg4, W1c4);
  enc_kernel<<<dim3(256), dim3(512), 0, stream>>>(p);
}